// Round 2
// baseline (165.654 us; speedup 1.0000x reference)
//
#include <hip/hip_runtime.h>
#include <stdint.h>

// out[n,o] = sum_{d,i} q[n,d] x[n,i] W1[d,i,o] + (q @ b1)[n,o]
// GEMM M=4096 N=256 K=16384 (k = d*256+i), fp16 MFMA 32x32x16, fp32 accum.
// A-frag = x-frag (LDS-resident) * q[row,d] (per-lane scalar, v_pk_mul_f16).
// K-loop is BARRIER-FREE: W chunks staged into per-wave private LDS buffers
// (each wave only ever reads its own 64-col slice), self-synced with
// s_waitcnt vmcnt(4). Chunk order ic-outer/d-inner so x-frags are register-
// cached across 8 d-iterations (halves LDS read traffic).

typedef _Float16 f16;
typedef f16 f16x8 __attribute__((ext_vector_type(8)));
typedef float f32x16 __attribute__((ext_vector_type(16)));

#define NROWS 4096
#define QDIM 64
#define SPLIT 8
#define MBLK 64
#define CHB 64  // chunks (BK=32) per split group

__device__ __forceinline__ void gl_lds16(const void* g, void* s) {
  __builtin_amdgcn_global_load_lds(
      (const __attribute__((address_space(1))) void*)(uintptr_t)g,
      (__attribute__((address_space(3))) void*)(uint32_t)(uintptr_t)s,
      16, 0, 0);
}

// ---- merged prep: [0,512) W reorder+cvt | [512,640) x cvt | [640,1664) bias ----
// Wt chunk index g = sg*64 + ic*8 + dd  (ic-outer streaming order for mlp_main)
// chunk layout: element ((s*2+h)*256 + n)*8 + j <- W1[(d*256+ic*32+s*16+h*8+j)*256+n]
__global__ __launch_bounds__(256) void prep(const float* __restrict__ W,
                                            const float* __restrict__ X,
                                            const float* __restrict__ Q,
                                            const float* __restrict__ B1,
                                            f16* __restrict__ Wt,
                                            f16* __restrict__ Xt,
                                            float* __restrict__ out) {
  const int b = blockIdx.x;
  const int t = threadIdx.x;
  if (b < 512) {
    const int sg = b >> 6, ic = (b >> 3) & 7, dd = b & 7;
    const int k0 = ((sg << 3) + dd) * 256 + (ic << 5);
#pragma unroll
    for (int r = 0; r < 4; ++r) {
      const int gidx = (r << 8) + t;  // (s*2+h)*256 + n
      const int n = gidx & 255;
      const int sh = gidx >> 8;
      f16x8 h;
#pragma unroll
      for (int j = 0; j < 8; ++j)
        h[j] = (f16)W[(size_t)(k0 + (sh << 3) + j) * 256 + n];  // coalesced over n
      *(f16x8*)(Wt + (size_t)b * 8192 + (size_t)gidx * 8) = h;
    }
  } else if (b < 640) {
    // x fp32 -> fragment-major fp16: Xt[mb][((ic*4+s*2+h)*64+row)*8+j] = x[mb*64+row][ic*32+s*16+h*8+j]
    const int bb = b - 512;
    const int mb = bb >> 1, half = bb & 1;
#pragma unroll
    for (int r = 0; r < 4; ++r) {
      const int gidx = (half << 10) + (r << 8) + t;  // f16x8 unit 0..2047
      const int row = gidx & 63;
      const int hsic = gidx >> 6;
      const float* src = X + (size_t)((mb << 6) + row) * 256 + (hsic << 3);
      float4 a = *(const float4*)src;
      float4 c = *(const float4*)(src + 4);
      f16x8 h;
      h[0] = (f16)a.x; h[1] = (f16)a.y; h[2] = (f16)a.z; h[3] = (f16)a.w;
      h[4] = (f16)c.x; h[5] = (f16)c.y; h[6] = (f16)c.z; h[7] = (f16)c.w;
      *(f16x8*)(Xt + (size_t)mb * 16384 + (size_t)gidx * 8) = h;
    }
  } else {
    // bias: 1024 blocks x 4 rows; wave = one row (q row in SGPRs), B1 rows L1-hot
    const int n0 = (b - 640) << 2;
    const int row = __builtin_amdgcn_readfirstlane(n0 + (t >> 6));  // wave-uniform
    const int col0 = (t & 63) << 2;
    float qv[64];
#pragma unroll
    for (int k = 0; k < 16; ++k) {
      float4 v = *(const float4*)(Q + (size_t)row * QDIM + (k << 2));
      qv[4 * k] = v.x; qv[4 * k + 1] = v.y; qv[4 * k + 2] = v.z; qv[4 * k + 3] = v.w;
    }
    float4 acc = {0.f, 0.f, 0.f, 0.f};
#pragma unroll 8
    for (int d = 0; d < 64; ++d) {
      float4 bv = *(const float4*)(B1 + d * 256 + col0);
      acc.x += qv[d] * bv.x; acc.y += qv[d] * bv.y;
      acc.z += qv[d] * bv.z; acc.w += qv[d] * bv.w;
    }
    *(float4*)(out + (size_t)row * 256 + col0) = acc;
  }
}

// ---- main GEMM: 512 blocks = 8 split-K groups (XCD-affine) x 64 row-blocks ----
__global__ __launch_bounds__(256, 2) void mlp_main(const float* __restrict__ Q,
                                                   const f16* __restrict__ Wt,
                                                   const f16* __restrict__ Xt,
                                                   float* __restrict__ out) {
  __shared__ f16 s_x[16384];       // 32 KB x tile, read-only after one barrier
  __shared__ f16 s_w[4][2][2048];  // per-wave double buffer: 4 waves x 2 x 4 KB

  const int bid = blockIdx.x;
  const int sg = bid & 7;   // all 64 blocks of a split group land on one XCD (%8)
  const int mb = bid >> 3;
  const int t = threadIdx.x;
  const int w = t >> 6;
  const int l = t & 63;
  const int l31 = l & 31;
  const int hf = l >> 5;

  // stage x tile (32 KB) cooperatively
  const char* xg = (const char*)(Xt + (size_t)mb * 16384);
  char* xs = (char*)s_x;
#pragma unroll
  for (int i = 0; i < 8; ++i) {
    const int off = (((w << 3) + i) << 10) + (l << 4);
    gl_lds16(xg + off, xs + off);
  }
  // stage chunk 0's per-wave slice (4 KB: this wave's 64 cols)
  const char* wg = (const char*)(Wt + (size_t)sg * (CHB * 8192));
  char* ws = (char*)&s_w[w][0][0];
#pragma unroll
  for (int i = 0; i < 4; ++i)
    gl_lds16(wg + (i << 12) + (w << 10) + (l << 4), ws + (i << 10) + (l << 4));

  // per-lane q scalars: q[mb*64 + mt*32 + l31][sg*8 + dd]
  f16 qr[2][8];
#pragma unroll
  for (int mt = 0; mt < 2; ++mt) {
    const float* qp = Q + (size_t)((mb << 6) + (mt << 5) + l31) * QDIM + (sg << 3);
#pragma unroll
    for (int dd = 0; dd < 8; ++dd) qr[mt][dd] = (f16)qp[dd];
  }

  f32x16 acc[2][2];
#pragma unroll
  for (int a = 0; a < 2; ++a)
#pragma unroll
    for (int bq = 0; bq < 2; ++bq)
#pragma unroll
      for (int r = 0; r < 16; ++r) acc[a][bq][r] = 0.f;

  __syncthreads();  // drains vmcnt(0): x tile + chunk 0 visible. ONLY barrier.

  const int wrd = (hf << 10) + (l31 << 4);  // per-lane base within (buf, s-region)

  for (int ic = 0; ic < 8; ++ic) {
    // x-frags for this ic, reused across 8 d-iterations
    f16x8 xf[2][2];
#pragma unroll
    for (int s = 0; s < 2; ++s)
#pragma unroll
      for (int mt = 0; mt < 2; ++mt)
        xf[mt][s] = *(const f16x8*)(s_x +
            ((((ic << 2) + (s << 1) + hf) << 6) + (mt << 5) + l31) * 8);
#pragma unroll
    for (int dd = 0; dd < 8; ++dd) {
      const int c = (ic << 3) + dd;
      const int nc = (c + 1) & 63;  // wrap-around prefetch keeps vmcnt pattern constant
      char* rbuf = ws + ((c & 1) << 12);
      char* nbuf = ws + (((c + 1) & 1) << 12);
      // issue prefetch of chunk c+1 slice into the other buffer (read c-1 iters ago)
#pragma unroll
      for (int i = 0; i < 4; ++i)
        gl_lds16(wg + ((size_t)nc << 14) + (i << 12) + (w << 10) + (l << 4),
                 nbuf + (i << 10) + (l << 4));
      // a-frags (independent of W) hide the wait
      const f16 qa0 = qr[0][dd], qa1 = qr[1][dd];
      f16x8 a00 = xf[0][0] * qa0, a10 = xf[1][0] * qa1;
      f16x8 a01 = xf[0][1] * qa0, a11 = xf[1][1] * qa1;
      // wait: chunk c arrived (4 newest loads = chunk c+1 may stay in flight)
      __builtin_amdgcn_s_waitcnt(0x0F74);  // vmcnt(4), lgkm/exp unlimited
      __builtin_amdgcn_sched_barrier(0);   // pin: no ds_read hoisted above wait
      f16x8 bf00 = *(const f16x8*)(rbuf + wrd);                  // s=0, nt=0
      f16x8 bf01 = *(const f16x8*)(rbuf + wrd + (1 << 9));       // s=0, nt=1
      f16x8 bf10 = *(const f16x8*)(rbuf + (2 << 10) + wrd);      // s=1, nt=0
      f16x8 bf11 = *(const f16x8*)(rbuf + (2 << 10) + wrd + (1 << 9));
      acc[0][0] = __builtin_amdgcn_mfma_f32_32x32x16_f16(a00, bf00, acc[0][0], 0, 0, 0);
      acc[1][0] = __builtin_amdgcn_mfma_f32_32x32x16_f16(a10, bf00, acc[1][0], 0, 0, 0);
      acc[0][1] = __builtin_amdgcn_mfma_f32_32x32x16_f16(a00, bf01, acc[0][1], 0, 0, 0);
      acc[1][1] = __builtin_amdgcn_mfma_f32_32x32x16_f16(a10, bf01, acc[1][1], 0, 0, 0);
      acc[0][0] = __builtin_amdgcn_mfma_f32_32x32x16_f16(a01, bf10, acc[0][0], 0, 0, 0);
      acc[1][0] = __builtin_amdgcn_mfma_f32_32x32x16_f16(a11, bf10, acc[1][0], 0, 0, 0);
      acc[0][1] = __builtin_amdgcn_mfma_f32_32x32x16_f16(a01, bf11, acc[0][1], 0, 0, 0);
      acc[1][1] = __builtin_amdgcn_mfma_f32_32x32x16_f16(a11, bf11, acc[1][1], 0, 0, 0);
    }
  }

  // drain stray wrap-around prefetch before LDS dealloc / kernel end
  __builtin_amdgcn_s_waitcnt(0x0F70);  // vmcnt(0)

  // epilogue: atomic split-K accumulate onto bias-initialized out.
  // C/D (32x32): col = lane&31, row = (reg&3) + 8*(reg>>2) + 4*(lane>>5)
#pragma unroll
  for (int mt = 0; mt < 2; ++mt) {
#pragma unroll
    for (int nt = 0; nt < 2; ++nt) {
#pragma unroll
      for (int r = 0; r < 16; ++r) {
        const int row = (mb << 6) + (mt << 5) + (r & 3) + ((r >> 2) << 3) + (hf << 2);
        const int col = (w << 6) + (nt << 5) + l31;
        atomicAdd(out + (size_t)row * 256 + col, acc[mt][nt][r]);
      }
    }
  }
}

extern "C" void kernel_launch(void* const* d_in, const int* in_sizes, int n_in,
                              void* d_out, int out_size, void* d_ws, size_t ws_size,
                              hipStream_t stream) {
  (void)in_sizes; (void)n_in; (void)out_size; (void)ws_size;
  const float* x  = (const float*)d_in[0];   // [4096,256]
  const float* q  = (const float*)d_in[1];   // [4096,64]
  const float* W1 = (const float*)d_in[2];   // [64,256,256]
  const float* b1 = (const float*)d_in[3];   // [64,256]
  float* out = (float*)d_out;                // [4096,256] fp32

  f16* Wt = (f16*)d_ws;                                   // 8 MB
  f16* Xt = (f16*)((char*)d_ws + (size_t)512 * 8192 * 2); // 2 MB @ +8MB

  prep<<<1664, 256, 0, stream>>>(W1, x, q, b1, Wt, Xt, out);
  mlp_main<<<(NROWS / MBLK) * SPLIT, 256, 0, stream>>>(q, Wt, Xt, out);
}

// Round 3
// 132.866 us; speedup vs baseline: 1.2468x; 1.2468x over previous
//
#include <hip/hip_runtime.h>
#include <stdint.h>

// out[n,o] = sum_{d,i} q[n,d] x[n,i] W1[d,i,o] + (q @ b1)[n,o]
// GEMM M=4096 N=256 K=16384 (k=d*256+i), fp16 MFMA 32x32x16, fp32 accum.
// A-frag = x-frag (LDS-resident) * q[row,d] per-lane scalar (v_pk_mul_f16).
// Bias q@b1 folded into split-group 0 as 2 extra K-chunks with A-frag = q-frag.
// K-loop barrier-free: per-wave private LDS W buffers (each wave reads only its
// own 64-col slice), depth-2 prefetch (3 buffers), self-sync s_waitcnt vmcnt(8).

typedef _Float16 f16;
typedef f16 f16x8 __attribute__((ext_vector_type(8)));
typedef float f32x16 __attribute__((ext_vector_type(16)));

#define NROWS 4096
#define QDIM 64
#define SPLIT 8
#define MBLK 64

__device__ __forceinline__ void gl_lds16(const void* g, void* s) {
  __builtin_amdgcn_global_load_lds(
      (const __attribute__((address_space(1))) void*)(uintptr_t)g,
      (__attribute__((address_space(3))) void*)(uint32_t)(uintptr_t)s,
      16, 0, 0);
}

// Wt chunk map: sg0 -> chunks 0..63, bias(b1) -> 64,65, sg>=1 -> 66+(sg-1)*64 ...
// chunk layout (16 KB): element ((s*2+h)*256+n)*8+j  <-  B[k = s*16+h*8+j][n]
// prep grid 658: [0,512) W | [512,640) x | [640,656) q->Qt | [656,658) b1
__global__ __launch_bounds__(256) void prep(const float* __restrict__ W,
                                            const float* __restrict__ X,
                                            const float* __restrict__ Q,
                                            const float* __restrict__ B1,
                                            f16* __restrict__ Wt,
                                            f16* __restrict__ Xt,
                                            f16* __restrict__ Qt) {
  const int b = blockIdx.x;
  const int t = threadIdx.x;
  if (b < 512) {
    const int sg = b >> 6, ic = (b >> 3) & 7, dd = b & 7;
    const int g = b + (sg ? 2 : 0);  // skip the 2 bias chunks
    const int k0 = ((sg << 3) + dd) * 256 + (ic << 5);
#pragma unroll
    for (int r = 0; r < 4; ++r) {
      const int gidx = (r << 8) + t;  // (s*2+h)*256 + n
      const int n = gidx & 255;
      const int sh = gidx >> 8;
      f16x8 h;
#pragma unroll
      for (int j = 0; j < 8; ++j)
        h[j] = (f16)W[(size_t)(k0 + (sh << 3) + j) * 256 + n];  // coalesced over n
      *(f16x8*)(Wt + (size_t)g * 8192 + (size_t)gidx * 8) = h;
    }
  } else if (b < 640) {
    // Xt[mb][((hsic)*64+row)*8+j] = x[mb*64+row][hsic*8+j]
    const int bb = b - 512;
    const int mb = bb >> 1, half = bb & 1;
#pragma unroll
    for (int r = 0; r < 4; ++r) {
      const int gidx = (half << 10) + (r << 8) + t;
      const int row = gidx & 63;
      const int hsic = gidx >> 6;
      const float* src = X + (size_t)((mb << 6) + row) * 256 + (hsic << 3);
      float4 a = *(const float4*)src;
      float4 c = *(const float4*)(src + 4);
      f16x8 h;
      h[0] = (f16)a.x; h[1] = (f16)a.y; h[2] = (f16)a.z; h[3] = (f16)a.w;
      h[4] = (f16)c.x; h[5] = (f16)c.y; h[6] = (f16)c.z; h[7] = (f16)c.w;
      *(f16x8*)(Xt + (size_t)mb * 16384 + (size_t)gidx * 8) = h;
    }
  } else if (b < 656) {
    // Qt[mb][(sh*64+row)*8+j] = q[mb*64+row][sh*8+j]  (A-operand layout, 64 k's)
    const int bb = b - 640;  // 0..15, 4 mb each
#pragma unroll
    for (int m = 0; m < 4; ++m) {
      const int mb = (bb << 2) + m;
#pragma unroll
      for (int r = 0; r < 2; ++r) {
        const int u = (r << 8) + t;  // 0..511
        const int row = u & 63;
        const int sh = u >> 6;
        const float* src = Q + (size_t)((mb << 6) + row) * QDIM + (sh << 3);
        float4 a = *(const float4*)src;
        float4 c = *(const float4*)(src + 4);
        f16x8 h;
        h[0] = (f16)a.x; h[1] = (f16)a.y; h[2] = (f16)a.z; h[3] = (f16)a.w;
        h[4] = (f16)c.x; h[5] = (f16)c.y; h[6] = (f16)c.z; h[7] = (f16)c.w;
        *(f16x8*)(Qt + (size_t)mb * 4096 + (size_t)u * 8) = h;
      }
    }
  } else {
    // b1 -> Wt chunks 64,65: B[k=cc*32+sh*8+j][n] = b1[k][n]
    const int cc = b - 656;
#pragma unroll
    for (int r = 0; r < 4; ++r) {
      const int gidx = (r << 8) + t;
      const int n = gidx & 255;
      const int sh = gidx >> 8;
      f16x8 h;
#pragma unroll
      for (int j = 0; j < 8; ++j)
        h[j] = (f16)B1[(size_t)((cc << 5) + (sh << 3) + j) * 256 + n];
      *(f16x8*)(Wt + (size_t)(64 + cc) * 8192 + (size_t)gidx * 8) = h;
    }
  }
}

// ---- main GEMM: 512 blocks = 8 split groups (XCD-affine %8) x 64 row-blocks ----
__global__ __launch_bounds__(256, 2) void mlp_main(const float* __restrict__ Q,
                                                   const f16* __restrict__ Wt,
                                                   const f16* __restrict__ Xt,
                                                   const f16* __restrict__ Qt,
                                                   float* __restrict__ out) {
  __shared__ f16 s_x[16384];       // 32 KB x tile (read-only after one barrier)
  __shared__ f16 s_w[4][3][2048];  // per-wave triple buffer: 4 waves x 3 x 4 KB

  const int bid = blockIdx.x;
  const int sg = bid & 7;
  const int mb = bid >> 3;
  const int t = threadIdx.x;
  const int w = t >> 6;
  const int l = t & 63;
  const int l31 = l & 31;
  const int hf = l >> 5;
  const int chunks = (sg == 0) ? 66 : 64;
  const char* wg = (const char*)(Wt + (size_t)((sg << 6) + (sg ? 2 : 0)) * 8192);

  // stage x tile (32 KB) cooperatively
  const char* xg = (const char*)(Xt + (size_t)mb * 16384);
  char* xs = (char*)s_x;
#pragma unroll
  for (int i = 0; i < 8; ++i) {
    const int off = (((w << 3) + i) << 10) + (l << 4);
    gl_lds16(xg + off, xs + off);
  }
  // stage chunks 0,1 into per-wave buffers 0,1
  char* ws0 = (char*)&s_w[w][0][0];
#pragma unroll
  for (int c0 = 0; c0 < 2; ++c0)
#pragma unroll
    for (int i = 0; i < 4; ++i)
      gl_lds16(wg + ((size_t)c0 << 14) + (i << 12) + (w << 10) + (l << 4),
               ws0 + (c0 << 12) + (i << 10) + (l << 4));

  // per-lane q scalars: q[mb*64 + mt*32 + l31][sg*8 + dd]
  f16 qr[2][8];
#pragma unroll
  for (int mt = 0; mt < 2; ++mt) {
    const float* qp = Q + (size_t)((mb << 6) + (mt << 5) + l31) * QDIM + (sg << 3);
#pragma unroll
    for (int dd = 0; dd < 8; ++dd) qr[mt][dd] = (f16)qp[dd];
  }

  // bias A-frags (sg0 only): qf[cc][mt][s] in MFMA A layout, k = cc*32+s*16+hf*8+j
  f16x8 qf[2][2][2];
  if (sg == 0) {
#pragma unroll
    for (int cc = 0; cc < 2; ++cc)
#pragma unroll
      for (int mt = 0; mt < 2; ++mt)
#pragma unroll
        for (int s = 0; s < 2; ++s)
          qf[cc][mt][s] = *(const f16x8*)(Qt + (size_t)mb * 4096 +
              (size_t)(((((cc << 1) + s) << 1) + hf) * 64 + (mt << 5) + l31) * 8);
  }

  f32x16 acc[2][2];
#pragma unroll
  for (int a = 0; a < 2; ++a)
#pragma unroll
    for (int bq = 0; bq < 2; ++bq)
#pragma unroll
      for (int r = 0; r < 16; ++r) acc[a][bq][r] = 0.f;

  __syncthreads();  // drains vmcnt(0): x tile + chunks 0,1 + qf visible. ONLY barrier.

  const int wrd = (hf << 10) + (l31 << 4);  // lane offset within (buf, s-region)
  const char* rb = ws0;           // chunk c (ready)
  const char* pb = ws0 + 4096;    // chunk c+1 (in flight or ready)
  char* fb = ws0 + 8192;          // receives chunk c+2
  int pc = 2;                     // next chunk to prefetch

  for (int ic = 0; ic < 8; ++ic) {
    f16x8 xf[2][2];  // x-frags reused across 8 d-iterations
#pragma unroll
    for (int s = 0; s < 2; ++s)
#pragma unroll
      for (int mt = 0; mt < 2; ++mt)
        xf[mt][s] = *(const f16x8*)(s_x +
            ((((ic << 2) + (s << 1) + hf) << 6) + (mt << 5) + l31) * 8);
#pragma unroll
    for (int dd = 0; dd < 8; ++dd) {
      // prefetch chunk pc into fb (depth-2: pc = c+2)
      const char* src = wg + ((size_t)pc << 14);
#pragma unroll
      for (int i = 0; i < 4; ++i)
        gl_lds16(src + (i << 12) + (w << 10) + (l << 4),
                 fb + (i << 10) + (l << 4));
      pc = (pc + 1 < chunks) ? pc + 1 : 0;  // wrap stays in-slab (harmless reload)
      // a-frags (independent of W) help hide the wait
      const f16 qa0 = qr[0][dd], qa1 = qr[1][dd];
      f16x8 a00 = xf[0][0] * qa0, a10 = xf[1][0] * qa1;
      f16x8 a01 = xf[0][1] * qa0, a11 = xf[1][1] * qa1;
      __builtin_amdgcn_s_waitcnt(0x0F78);  // vmcnt(8): chunk c arrived, c+1/c+2 in flight
      __builtin_amdgcn_sched_barrier(0);   // no ds_read hoisted above the wait
      f16x8 bf00 = *(const f16x8*)(rb + wrd);
      f16x8 bf01 = *(const f16x8*)(rb + wrd + (1 << 9));
      f16x8 bf10 = *(const f16x8*)(rb + (2 << 10) + wrd);
      f16x8 bf11 = *(const f16x8*)(rb + (2 << 10) + wrd + (1 << 9));
      acc[0][0] = __builtin_amdgcn_mfma_f32_32x32x16_f16(a00, bf00, acc[0][0], 0, 0, 0);
      acc[1][0] = __builtin_amdgcn_mfma_f32_32x32x16_f16(a10, bf00, acc[1][0], 0, 0, 0);
      acc[0][1] = __builtin_amdgcn_mfma_f32_32x32x16_f16(a00, bf01, acc[0][1], 0, 0, 0);
      acc[1][1] = __builtin_amdgcn_mfma_f32_32x32x16_f16(a10, bf01, acc[1][1], 0, 0, 0);
      acc[0][0] = __builtin_amdgcn_mfma_f32_32x32x16_f16(a01, bf10, acc[0][0], 0, 0, 0);
      acc[1][0] = __builtin_amdgcn_mfma_f32_32x32x16_f16(a11, bf10, acc[1][0], 0, 0, 0);
      acc[0][1] = __builtin_amdgcn_mfma_f32_32x32x16_f16(a01, bf11, acc[0][1], 0, 0, 0);
      acc[1][1] = __builtin_amdgcn_mfma_f32_32x32x16_f16(a11, bf11, acc[1][1], 0, 0, 0);
      // rotate triple buffer
      const char* tmp = rb; rb = pb; pb = fb; fb = (char*)tmp;
    }
  }

  // bias tail (sg0): 2 extra chunks, A-frag = q-frag (already in registers)
  if (sg == 0) {
#pragma unroll
    for (int cc = 0; cc < 2; ++cc) {
      const char* src = wg + ((size_t)pc << 14);  // wrapped prefetch: harmless
#pragma unroll
      for (int i = 0; i < 4; ++i)
        gl_lds16(src + (i << 12) + (w << 10) + (l << 4),
                 fb + (i << 10) + (l << 4));
      pc = (pc + 1 < chunks) ? pc + 1 : 0;
      __builtin_amdgcn_s_waitcnt(0x0F78);
      __builtin_amdgcn_sched_barrier(0);
      f16x8 bf00 = *(const f16x8*)(rb + wrd);
      f16x8 bf01 = *(const f16x8*)(rb + wrd + (1 << 9));
      f16x8 bf10 = *(const f16x8*)(rb + (2 << 10) + wrd);
      f16x8 bf11 = *(const f16x8*)(rb + (2 << 10) + wrd + (1 << 9));
      acc[0][0] = __builtin_amdgcn_mfma_f32_32x32x16_f16(qf[cc][0][0], bf00, acc[0][0], 0, 0, 0);
      acc[1][0] = __builtin_amdgcn_mfma_f32_32x32x16_f16(qf[cc][1][0], bf00, acc[1][0], 0, 0, 0);
      acc[0][1] = __builtin_amdgcn_mfma_f32_32x32x16_f16(qf[cc][0][0], bf01, acc[0][1], 0, 0, 0);
      acc[1][1] = __builtin_amdgcn_mfma_f32_32x32x16_f16(qf[cc][1][0], bf01, acc[1][1], 0, 0, 0);
      acc[0][0] = __builtin_amdgcn_mfma_f32_32x32x16_f16(qf[cc][0][1], bf10, acc[0][0], 0, 0, 0);
      acc[1][0] = __builtin_amdgcn_mfma_f32_32x32x16_f16(qf[cc][1][1], bf10, acc[1][0], 0, 0, 0);
      acc[0][1] = __builtin_amdgcn_mfma_f32_32x32x16_f16(qf[cc][0][1], bf11, acc[0][1], 0, 0, 0);
      acc[1][1] = __builtin_amdgcn_mfma_f32_32x32x16_f16(qf[cc][1][1], bf11, acc[1][1], 0, 0, 0);
      const char* tmp = rb; rb = pb; pb = fb; fb = (char*)tmp;
    }
  }

  __builtin_amdgcn_s_waitcnt(0x0F70);  // drain stray prefetches before LDS reuse/end

  // epilogue: atomic split-K accumulate onto zero-initialized out.
  // C/D (32x32): col = lane&31, row = (reg&3) + 8*(reg>>2) + 4*(lane>>5)
#pragma unroll
  for (int mt = 0; mt < 2; ++mt) {
#pragma unroll
    for (int nt = 0; nt < 2; ++nt) {
#pragma unroll
      for (int r = 0; r < 16; ++r) {
        const int row = (mb << 6) + (mt << 5) + (r & 3) + ((r >> 2) << 3) + (hf << 2);
        const int col = (w << 6) + (nt << 5) + l31;
        atomicAdd(out + (size_t)row * 256 + col, acc[mt][nt][r]);
      }
    }
  }
}

extern "C" void kernel_launch(void* const* d_in, const int* in_sizes, int n_in,
                              void* d_out, int out_size, void* d_ws, size_t ws_size,
                              hipStream_t stream) {
  (void)in_sizes; (void)n_in; (void)out_size; (void)ws_size;
  const float* x  = (const float*)d_in[0];   // [4096,256]
  const float* q  = (const float*)d_in[1];   // [4096,64]
  const float* W1 = (const float*)d_in[2];   // [64,256,256]
  const float* b1 = (const float*)d_in[3];   // [64,256]
  float* out = (float*)d_out;                // [4096,256] fp32

  // ws: Wt 514 chunks x 16 KB = 8.22 MB | Xt 2 MB | Qt 0.5 MB  (~10.8 MB total)
  f16* Wt = (f16*)d_ws;
  f16* Xt = (f16*)((char*)d_ws + (size_t)514 * 16384);
  f16* Qt = (f16*)((char*)d_ws + (size_t)514 * 16384 + (size_t)64 * 32768);

  hipMemsetAsync(out, 0, (size_t)NROWS * 256 * sizeof(float), stream);
  prep<<<658, 256, 0, stream>>>(W1, x, q, b1, Wt, Xt, Qt);
  mlp_main<<<(NROWS / MBLK) * SPLIT, 256, 0, stream>>>(q, Wt, Xt, Qt, out);
}